// Round 19
// baseline (279.103 us; speedup 1.0000x reference)
//
#include <hip/hip_runtime.h>
#include <stdint.h>

typedef _Float16 f16x8 __attribute__((ext_vector_type(8)));
typedef float    f32x4 __attribute__((ext_vector_type(4)));
typedef unsigned u32x4 __attribute__((ext_vector_type(4)));

union Frag { u32x4 q; f16x8 h; unsigned u[4]; };

static __device__ __forceinline__ unsigned short f2h(float f) {
  _Float16 h = (_Float16)f;
  return __builtin_bit_cast(unsigned short, h);
}
// u8 decode: bytes are q+128; h = max(qa+qb-256, 0), int in [0,254]
static __device__ __forceinline__ void dec4i(unsigned a, unsigned b, int* h) {
  unsigned lo = (a & 0x00FF00FFu) + (b & 0x00FF00FFu);
  unsigned hi = ((a >> 8) & 0x00FF00FFu) + ((b >> 8) & 0x00FF00FFu);
  int t0 = (int)(lo & 0xFFFFu) - 256;
  int t1 = (int)(hi & 0xFFFFu) - 256;
  int t2 = (int)(lo >> 16) - 256;
  int t3 = (int)(hi >> 16) - 256;
  h[0] = t0 > 0 ? t0 : 0; h[1] = t1 > 0 ? t1 : 0;
  h[2] = t2 > 0 ? t2 : 0; h[3] = t3 > 0 ? t3 : 0;
}
// magic decode for H8 stream: u32 bytes (h_k0,h_k2,h_k1,h_k3) -> two f16 pairs
// holding 1024+h exactly (offset folded into b2ps).
static __device__ __forceinline__ void mg2(unsigned y, unsigned& w0, unsigned& w1) {
  w0 = (y & 0x00FF00FFu) + 0x64006400u;
  w1 = ((y >> 8) & 0x00FF00FFu) + 0x64006400u;
}
// DPP quad-perm lane-xor add (VALU pipe, not LDS): xor1=0xB1, xor2=0x4E
template<int CTRL>
static __device__ __forceinline__ float dppadd(float s) {
  int v = __builtin_amdgcn_mov_dpp(__builtin_bit_cast(int, s), CTRL, 0xf, 0xf, true);
  return s + __builtin_bit_cast(float, v);
}

// ---------------- kernel 1: per-node projections (feature-per-thread) --
// Single GEMM pass: stores f32 projections Tf1/Tf2 (non-temporal; consumed
// once by k_quant) AND per-feature max.
__global__ __launch_bounds__(256) void k_nodeproj(
    const float* __restrict__ z, const float* __restrict__ c,
    const float* __restrict__ W1, const float* __restrict__ b1,
    unsigned* __restrict__ gmax1, unsigned* __restrict__ gmax2,
    float* __restrict__ Tf1, float* __restrict__ Tf2, int n_nodes) {
  __shared__ float zl[128 * 64];   // 32 KB
  const int t = threadIdx.x;
  const int j = t & 127;           // true feature
  const int half = t >> 7;
  const int nb = blockIdx.x * 128;
  {
    const float* zsrc = z + (size_t)nb * 64;
    const int limit = (n_nodes - nb) * 64;
    for (int i = t; i < 2048; i += 256) {
      f32x4 v = {0.f, 0.f, 0.f, 0.f};
      if (i * 4 + 3 < limit) {
        v = *(const f32x4*)(zsrc + i * 4);
      } else {
        #pragma unroll
        for (int q = 0; q < 4; ++q) if (i * 4 + q < limit) v[q] = zsrc[i * 4 + q];
      }
      *(f32x4*)(zl + i * 4) = v;
    }
  }
  float kvj = b1[j];
  #pragma unroll
  for (int q = 0; q < 4; ++q) kvj += c[q] * W1[(128 + q) * 128 + j];
  __syncthreads();

  float wreg[64];
  // ---- half A: T1 (W1 rows 0..63), bias kvj ----
  #pragma unroll
  for (int d = 0; d < 64; ++d) wreg[d] = W1[d * 128 + j];
  float mx = 0.f;
  for (int i = 0; i < 64; ++i) {
    const int n = i * 2 + half;
    const int gn = nb + n;
    float acc = kvj;
    #pragma unroll
    for (int d4 = 0; d4 < 16; ++d4) {
      f32x4 zz = *(const f32x4*)(zl + n * 64 + d4 * 4);
      acc += zz[0]*wreg[d4*4+0] + zz[1]*wreg[d4*4+1]
           + zz[2]*wreg[d4*4+2] + zz[3]*wreg[d4*4+3];
    }
    if (gn < n_nodes) {
      __builtin_nontemporal_store(acc, Tf1 + (size_t)gn * 128 + j);
      mx = fmaxf(mx, fabsf(acc));
    }
  }
  atomicMax(&gmax1[j], __float_as_uint(mx));
  // ---- half B: T2 (W1 rows 64..127), no bias ----
  #pragma unroll
  for (int d = 0; d < 64; ++d) wreg[d] = W1[(64 + d) * 128 + j];
  mx = 0.f;
  for (int i = 0; i < 64; ++i) {
    const int n = i * 2 + half;
    const int gn = nb + n;
    float acc = 0.f;
    #pragma unroll
    for (int d4 = 0; d4 < 16; ++d4) {
      f32x4 zz = *(const f32x4*)(zl + n * 64 + d4 * 4);
      acc += zz[0]*wreg[d4*4+0] + zz[1]*wreg[d4*4+1]
           + zz[2]*wreg[d4*4+2] + zz[3]*wreg[d4*4+3];
    }
    if (gn < n_nodes) {
      __builtin_nontemporal_store(acc, Tf2 + (size_t)gn * 128 + j);
      mx = fmaxf(mx, fabsf(acc));
    }
  }
  atomicMax(&gmax2[j], __float_as_uint(mx));
}

// ---------------- kernel 1b: streaming quantize Tf -> permuted u8 -----
__global__ __launch_bounds__(256) void k_quant(
    const float* __restrict__ Tf1, const float* __restrict__ Tf2,
    const unsigned* __restrict__ g1, const unsigned* __restrict__ g2,
    unsigned char* __restrict__ U1, unsigned char* __restrict__ U2,
    int n_nodes) {
  const int tid = blockIdx.x * 256 + threadIdx.x;
  const int tot = n_nodes * 8;
  if (tid >= 2 * tot) return;
  const int table = tid >= tot;
  const int r = tid - table * tot;
  const int node = r >> 3, g = r & 7;
  const float* src = (table ? Tf2 : Tf1) + (size_t)node * 128 + g * 16;
  unsigned char* dst = (table ? U2 : U1) + (size_t)node * 128;
  f32x4 v[4];
  #pragma unroll
  for (int q = 0; q < 4; ++q)
    v[q] = __builtin_nontemporal_load((const f32x4*)(src + q * 4));
  #pragma unroll
  for (int b = 0; b < 2; ++b) {
    unsigned w0 = 0, w1 = 0;
    #pragma unroll
    for (int k = 0; k < 8; ++k) {
      const int f = g * 16 + b * 8 + k;
      float m = fmaxf(fmaxf(__uint_as_float(g1[f]), __uint_as_float(g2[f])),
                      1e-20f);
      float dij = 127.0f / m;
      float acc = v[b * 2 + (k >> 2)][k & 3];
      int q8 = (int)rintf(acc * dij);
      q8 = q8 > 127 ? 127 : (q8 < -127 ? -127 : q8);
      unsigned by = (unsigned)(q8 + 128);
      if (k < 4) w0 |= by << (8 * k); else w1 |= by << (8 * (k - 4));
    }
    const int off = (((2 * g + b) & 3) * 32) + ((g >> 1) * 8);
    *(unsigned*)(dst + off)     = w0;    // cached: gathered repeatedly later
    *(unsigned*)(dst + off + 4) = w1;
  }
}

// ---------------- kernel 2: BN stats, 2-deep gather pipeline ----------
// Block-level int sums -> ONE 64-bit atomicAdd per slot (integer adds are
// order-independent -> bitwise deterministic). H8 written NON-TEMPORAL so
// the 207 MB stream doesn't evict the 12.8 MB gather tables from L2/L3.
template<int WH8>
__global__ __launch_bounds__(512) void k_stats(
    const int* __restrict__ ei, const unsigned char* __restrict__ U1,
    const unsigned char* __restrict__ U2,
    unsigned long long* __restrict__ gstat,
    unsigned char* __restrict__ H8, int E, int niter16) {
  __shared__ int red[8][256];
  const int t = threadIdx.x;
  const int w = t >> 6, l = t & 63;
  const int es = l >> 3, ch = l & 7;
  int sm[16], sq[16];
  #pragma unroll
  for (int k = 0; k < 16; ++k) { sm[k] = 0; sq[k] = 0; }
  const int nw = gridDim.x * 8;
  int itc = blockIdx.x * 8 + w;
  int itn = itc + nw;
  u32x4 a0c, b0c, a1c, b1c, a0n, b0n, a1n, b1n;
  int ns0 = 0, nd0 = 0, ns1 = 0, nd1 = 0;
  if (itc < niter16) {
    const int e = itc * 16;
    int s0 = ei[e + es],     d0 = ei[E + e + es];
    int s1 = ei[e + 8 + es], d1 = ei[E + e + 8 + es];
    a0c = *(const u32x4*)(U1 + (size_t)s0 * 128 + ch * 16);
    b0c = *(const u32x4*)(U2 + (size_t)d0 * 128 + ch * 16);
    a1c = *(const u32x4*)(U1 + (size_t)s1 * 128 + ch * 16);
    b1c = *(const u32x4*)(U2 + (size_t)d1 * 128 + ch * 16);
  }
  if (itn < niter16) {
    const int e = itn * 16;
    ns0 = ei[e + es];     nd0 = ei[E + e + es];
    ns1 = ei[e + 8 + es]; nd1 = ei[E + e + 8 + es];
  }
  while (itc < niter16) {
    const bool vn = itn < niter16;
    if (vn) {
      a0n = *(const u32x4*)(U1 + (size_t)ns0 * 128 + ch * 16);
      b0n = *(const u32x4*)(U2 + (size_t)nd0 * 128 + ch * 16);
      a1n = *(const u32x4*)(U1 + (size_t)ns1 * 128 + ch * 16);
      b1n = *(const u32x4*)(U2 + (size_t)nd1 * 128 + ch * 16);
      const int it2 = itn + nw;
      if (it2 < niter16) {
        const int e = it2 * 16;
        ns0 = ei[e + es];     nd0 = ei[E + e + es];
        ns1 = ei[e + 8 + es]; nd1 = ei[E + e + 8 + es];
      }
    }
    const int e16 = itc * 16;
    u32x4 o0, o1;
    #pragma unroll
    for (int qq = 0; qq < 4; ++qq) {
      int h[4];
      dec4i(a0c[qq], b0c[qq], h);
      #pragma unroll
      for (int r = 0; r < 4; ++r) { sm[qq*4+r] += h[r]; sq[qq*4+r] += h[r]*h[r]; }
      if (WH8) o0[qq] = (unsigned)h[0] | ((unsigned)h[2] << 8)
                      | ((unsigned)h[1] << 16) | ((unsigned)h[3] << 24);
      dec4i(a1c[qq], b1c[qq], h);
      #pragma unroll
      for (int r = 0; r < 4; ++r) { sm[qq*4+r] += h[r]; sq[qq*4+r] += h[r]*h[r]; }
      if (WH8) o1[qq] = (unsigned)h[0] | ((unsigned)h[2] << 8)
                      | ((unsigned)h[1] << 16) | ((unsigned)h[3] << 24);
    }
    if (WH8) {
      __builtin_nontemporal_store(o0,
          (u32x4*)(H8 + (size_t)(e16 + es) * 128 + ch * 16));
      __builtin_nontemporal_store(o1,
          (u32x4*)(H8 + (size_t)(e16 + 8 + es) * 128 + ch * 16));
    }
    if (!vn) break;
    a0c = a0n; b0c = b0n; a1c = a1n; b1c = b1n;
    itc = itn; itn += nw;
  }
  #pragma unroll
  for (int k = 0; k < 16; ++k) {
    sm[k] += __shfl_xor(sm[k], 8, 64);
    sm[k] += __shfl_xor(sm[k], 16, 64);
    sm[k] += __shfl_xor(sm[k], 32, 64);
    sq[k] += __shfl_xor(sq[k], 8, 64);
    sq[k] += __shfl_xor(sq[k], 16, 64);
    sq[k] += __shfl_xor(sq[k], 32, 64);
  }
  if (es == 0) {
    #pragma unroll
    for (int k = 0; k < 16; ++k) {
      int f = ((ch & 1) * 2 + (k >> 3)) * 32 + (ch >> 1) * 8 + (k & 7);
      red[w][f]       = sm[k];
      red[w][128 + f] = sq[k];
    }
  }
  __syncthreads();
  if (t < 256) {
    long long s = 0;
    #pragma unroll
    for (int ww = 0; ww < 8; ++ww) s += red[ww][t];
    atomicAdd(&gstat[t], (unsigned long long)s);
  }
}

// ---------------- kernel 3: finalize BN + fold scale into W2 ----------
__global__ __launch_bounds__(1024) void k_finalize(
    const unsigned long long* __restrict__ gstat,
    const float* __restrict__ gamma, const float* __restrict__ beta,
    const float* __restrict__ W2, const float* __restrict__ b2,
    const unsigned* __restrict__ gmax1, const unsigned* __restrict__ gmax2,
    unsigned short* __restrict__ W2t, float* __restrict__ b2p,
    float* __restrict__ b2ps, double Einv) {
  __shared__ float ajd[128], bbj[128];
  __shared__ float bacc[8][128];
  const int t = threadIdx.x;
  if (t < 128) {
    float m = fmaxf(fmaxf(__uint_as_float(gmax1[t]), __uint_as_float(gmax2[t])),
                    1e-20f);
    double d8 = (double)(m * (1.0f / 127.0f));
    double mean = d8 * (double)gstat[t] * Einv;
    double ex2  = d8 * d8 * (double)gstat[128 + t] * Einv;
    double var  = ex2 - mean * mean;
    float a = (float)((double)gamma[t] / sqrt(var + 1e-5));
    ajd[t] = a * (float)d8;
    bbj[t] = beta[t] - (float)mean * a;
  }
  __syncthreads();
  for (int cidx = t; cidx < 16384; cidx += 1024) {
    int i = cidx >> 7;
    int j = cidx & 127;
    W2t[j * 128 + i] = f2h(ajd[i] * W2[cidx]);
  }
  {
    const int col = t & 127, g2 = t >> 7;
    float acc = 0.f;
    #pragma unroll
    for (int q = 0; q < 16; ++q) {
      int i = g2 * 16 + q;
      acc += bbj[i] * W2[i * 128 + col];
    }
    bacc[g2][col] = acc;
  }
  __syncthreads();
  if (t < 128) {
    float a = b2[t];
    #pragma unroll
    for (int g3 = 0; g3 < 8; ++g3) a += bacc[g3][t];
    b2p[t] = a;
    float c = 0.f;
    for (int i = 0; i < 128; ++i)
      c += (float)((_Float16)(ajd[i] * W2[i * 128 + t]));
    b2ps[t] = a - 1024.0f * c;
  }
}

// ---------------- kernel 4: streaming MFMA over H8, B in registers ----
// H8 read non-temporal (read-once stream); out written non-temporal.
__global__ __launch_bounds__(256) void k_edge_h8(
    const unsigned char* __restrict__ H8, const unsigned short* __restrict__ W2t,
    const float* __restrict__ b2ps, const float* __restrict__ W3,
    const float* __restrict__ b3, float* __restrict__ out, int ntiles) {
  const int t = threadIdx.x;
  const int w = t >> 6, l = t & 63;
  const int lm = l & 15, lg = l >> 4;
  const int lo32 = lg * 32;
  // loop-invariant B fragments: Bf[nt][s] = W2t row nt*16+lm, k-chunk s*4+lg
  Frag Bf[8][4];
  #pragma unroll
  for (int nt = 0; nt < 8; ++nt)
    #pragma unroll
    for (int s = 0; s < 4; ++s)
      Bf[nt][s].q = *(const u32x4*)((const char*)W2t +
                      (size_t)(nt*16 + lm) * 256 + s*64 + lg*16);
  float b2r[8], w3r[8];
  #pragma unroll
  for (int nt = 0; nt < 8; ++nt) {
    b2r[nt] = b2ps[nt*16 + lm];
    w3r[nt] = W3[nt*16 + lm];
  }
  const float b3v = *b3;
  const int stride = gridDim.x;
  int tile = blockIdx.x;
  if (tile >= ntiles) return;
  int ebase = tile*64 + w*16;
  u32x4 Y0, Y1, N0, N1;   // current / next staged rows (lane lm's edge)
  {
    const unsigned char* r0 = H8 + (size_t)(ebase + lm) * 128 + lo32;
    Y0 = __builtin_nontemporal_load((const u32x4*)r0);
    Y1 = __builtin_nontemporal_load((const u32x4*)(r0 + 16));
  }
  while (true) {
    const int next = tile + stride;
    const bool has_next = next < ntiles;
    const int pref = has_next ? next : tile;
    const int neb = pref*64 + w*16;
    {
      const unsigned char* n0 = H8 + (size_t)(neb + lm) * 128 + lo32;
      N0 = __builtin_nontemporal_load((const u32x4*)n0);
      N1 = __builtin_nontemporal_load((const u32x4*)(n0 + 16));
    }
    f32x4 acc[8];
    #pragma unroll
    for (int nt = 0; nt < 8; ++nt) {
      f32x4 zed = {0.f, 0.f, 0.f, 0.f};
      acc[nt] = zed;
    }
    Frag fa;
    #define MFMAS(S)                                                        \
      _Pragma("unroll")                                                     \
      for (int nt = 0; nt < 8; ++nt)                                        \
        acc[nt] = __builtin_amdgcn_mfma_f32_16x16x32_f16(fa.h, Bf[nt][S].h, \
                                                         acc[nt], 0, 0, 0);
    mg2(Y0[0], fa.u[0], fa.u[1]); mg2(Y0[1], fa.u[2], fa.u[3]);
    MFMAS(0)
    mg2(Y0[2], fa.u[0], fa.u[1]); mg2(Y0[3], fa.u[2], fa.u[3]);
    MFMAS(1)
    mg2(Y1[0], fa.u[0], fa.u[1]); mg2(Y1[1], fa.u[2], fa.u[3]);
    MFMAS(2)
    mg2(Y1[2], fa.u[0], fa.u[1]); mg2(Y1[3], fa.u[2], fa.u[3]);
    MFMAS(3)
    #undef MFMAS
    #pragma unroll
    for (int r = 0; r < 4; ++r) {
      float sum = 0.f;
      #pragma unroll
      for (int nt = 0; nt < 8; ++nt) {
        float h2 = fmaxf(acc[nt][r] + b2r[nt], 0.f);
        sum += h2 * w3r[nt];
      }
      sum = dppadd<0xB1>(sum);            // xor1 (quad_perm, VALU pipe)
      sum = dppadd<0x4E>(sum);            // xor2 (quad_perm, VALU pipe)
      sum += __shfl_xor(sum, 4, 64);
      sum += __shfl_xor(sum, 8, 64);
      if (lm == 0)
        __builtin_nontemporal_store(sum + b3v, out + ebase + lg*4 + r);
    }
    if (!has_next) break;
    tile = next;
    ebase = neb;
    Y0 = N0;  Y1 = N1;
  }
}

extern "C" void kernel_launch(void* const* d_in, const int* in_sizes, int n_in,
                              void* d_out, int out_size, void* d_ws, size_t ws_size,
                              hipStream_t stream) {
  const float* z     = (const float*)d_in[0];
  const int*   ei    = (const int*)d_in[1];
  const float* c     = (const float*)d_in[2];
  const float* W1    = (const float*)d_in[3];
  const float* b1    = (const float*)d_in[4];
  const float* gamma = (const float*)d_in[5];
  const float* beta  = (const float*)d_in[6];
  const float* W2    = (const float*)d_in[7];
  const float* b2    = (const float*)d_in[8];
  const float* W3    = (const float*)d_in[9];
  const float* b3    = (const float*)d_in[10];
  float* out = (float*)d_out;

  const int n_nodes = in_sizes[0] / 64;   // 50000
  const int E       = in_sizes[1] / 2;    // 1600000
  const int NB2 = 1024;

  char* ws = (char*)d_ws;
  const size_t nb128 = (size_t)n_nodes * 128;   // 6.4 MB per table
  unsigned char* U1 = (unsigned char*)ws;
  unsigned char* U2 = U1 + nb128;
  char* p = (char*)(U2 + nb128);
  unsigned short* W2t = (unsigned short*)p;      p += 32768;
  float* b2p          = (float*)p;               p += 512;
  float* b2ps         = (float*)p;               p += 512;
  unsigned* gmax1     = (unsigned*)p;            p += 512;
  unsigned* gmax2     = (unsigned*)p;            p += 512;
  unsigned long long* gstat = (unsigned long long*)p;  p += 2048;
  unsigned char* H8   = (unsigned char*)p;
  // Tf (f32 projections, 51.2 MB) lives in the H8 region: consumed by
  // k_quant BEFORE k_stats overwrites H8. Union is safe (stream-ordered).
  float* Tf1 = (float*)H8;
  float* Tf2 = Tf1 + (size_t)n_nodes * 128;
  const size_t need = (size_t)((char*)H8 - ws) + (size_t)E * 128;  // ~218 MB
  const bool use_h8 = (ws_size >= need);

  // zero gmax1(512) + gmax2(512) + gstat(2048) in one contiguous memset
  (void)hipMemsetAsync(gmax1, 0, 3072, stream);
  const int npb = (n_nodes + 127) / 128;
  k_nodeproj<<<npb, 256, 0, stream>>>(z, c, W1, b1, gmax1, gmax2,
                                      Tf1, Tf2, n_nodes);
  const int nqb = (n_nodes * 16 + 255) / 256;
  k_quant<<<nqb, 256, 0, stream>>>(Tf1, Tf2, gmax1, gmax2, U1, U2, n_nodes);
  if (use_h8)
    k_stats<1><<<NB2, 512, 0, stream>>>(ei, U1, U2, gstat, H8, E, E/16);
  else
    k_stats<0><<<NB2, 512, 0, stream>>>(ei, U1, U2, gstat, H8, E, E/16);
  k_finalize<<<1, 1024, 0, stream>>>(gstat, gamma, beta, W2, b2,
                                     gmax1, gmax2, W2t, b2p, b2ps,
                                     1.0 / (double)E);
  k_edge_h8<<<512, 256, 0, stream>>>(H8, W2t, b2ps, W3, b3, out, E/64);
}

// Round 20
// 234.218 us; speedup vs baseline: 1.1916x; 1.1916x over previous
//
#include <hip/hip_runtime.h>
#include <stdint.h>

typedef _Float16 f16x8 __attribute__((ext_vector_type(8)));
typedef float    f32x4 __attribute__((ext_vector_type(4)));
typedef unsigned u32x4 __attribute__((ext_vector_type(4)));

union Frag { u32x4 q; f16x8 h; unsigned u[4]; };

static __device__ __forceinline__ unsigned short f2h(float f) {
  _Float16 h = (_Float16)f;
  return __builtin_bit_cast(unsigned short, h);
}
static __device__ __forceinline__ unsigned packhf(float lo, float hi) {
  _Float16 a = (_Float16)lo, b = (_Float16)hi;
  unsigned short x = __builtin_bit_cast(unsigned short, a);
  unsigned short y = __builtin_bit_cast(unsigned short, b);
  return (unsigned)x | ((unsigned)y << 16);
}
// u8 decode: bytes are q+128; h = max(qa+qb-256, 0), int in [0,254]
static __device__ __forceinline__ void dec4i(unsigned a, unsigned b, int* h) {
  unsigned lo = (a & 0x00FF00FFu) + (b & 0x00FF00FFu);
  unsigned hi = ((a >> 8) & 0x00FF00FFu) + ((b >> 8) & 0x00FF00FFu);
  int t0 = (int)(lo & 0xFFFFu) - 256;
  int t1 = (int)(hi & 0xFFFFu) - 256;
  int t2 = (int)(lo >> 16) - 256;
  int t3 = (int)(hi >> 16) - 256;
  h[0] = t0 > 0 ? t0 : 0; h[1] = t1 > 0 ? t1 : 0;
  h[2] = t2 > 0 ? t2 : 0; h[3] = t3 > 0 ? t3 : 0;
}
// magic decode for H8 stream: u32 bytes (h_k0,h_k2,h_k1,h_k3) -> two f16 pairs
// holding 1024+h exactly (offset folded into b2ps).
static __device__ __forceinline__ void mg2(unsigned y, unsigned& w0, unsigned& w1) {
  w0 = (y & 0x00FF00FFu) + 0x64006400u;
  w1 = ((y >> 8) & 0x00FF00FFu) + 0x64006400u;
}
// DPP quad-perm lane-xor add (VALU pipe, not LDS): xor1=0xB1, xor2=0x4E
template<int CTRL>
static __device__ __forceinline__ float dppadd(float s) {
  int v = __builtin_amdgcn_mov_dpp(__builtin_bit_cast(int, s), CTRL, 0xf, 0xf, true);
  return s + __builtin_bit_cast(float, v);
}

// ---------------- kernel 0: pack W1 into f16 MFMA B-fragments + kv -----
// W1h entry e = frag*64 + lane; frag = h*16 + ks*8 + nt. Lane (lm,lg) holds
// B[k = ks*32+lg*8+j][n = nt*16+lm] = W1[h*64 + k][n], j = 0..7.
__global__ __launch_bounds__(256) void k_wprep(
    const float* __restrict__ W1, const float* __restrict__ b1,
    const float* __restrict__ c, unsigned short* __restrict__ W1h,
    float* __restrict__ kvbuf) {
  const int e = blockIdx.x * 256 + threadIdx.x;   // 0..2047
  const int frag = e >> 6, lane = e & 63;
  const int h = frag >> 4, ks = (frag >> 3) & 1, nt = frag & 7;
  const int lm = lane & 15, lg = lane >> 4;
  u32x4 ov;
  #pragma unroll
  for (int p = 0; p < 4; ++p) {
    unsigned short s0 = f2h(W1[(size_t)(h*64 + ks*32 + lg*8 + 2*p)     * 128 + nt*16 + lm]);
    unsigned short s1 = f2h(W1[(size_t)(h*64 + ks*32 + lg*8 + 2*p + 1) * 128 + nt*16 + lm]);
    ov[p] = (unsigned)s0 | ((unsigned)s1 << 16);
  }
  *(u32x4*)(W1h + (size_t)e * 8) = ov;
  if (blockIdx.x == 0 && threadIdx.x < 128) {
    const int f = threadIdx.x;
    float kv = b1[f];
    #pragma unroll
    for (int q = 0; q < 4; ++q) kv += c[q] * W1[(128 + q) * 128 + f];
    kvbuf[f] = kv;
  }
}

// ---------------- kernel 1: node projections via MFMA ------------------
// Wave handles one 16-node tile: A-frags from global z (f32->f16 in regs),
// B-frags from W1h, 32 MFMA; node-major f32 Tf stores (k_quant unchanged);
// per-feature max via LDS atomics -> global atomicMax.
__global__ __launch_bounds__(256) void k_npmfma(
    const float* __restrict__ z, const unsigned short* __restrict__ W1h,
    const float* __restrict__ kvbuf,
    unsigned* __restrict__ gmax1, unsigned* __restrict__ gmax2,
    float* __restrict__ Tf1, float* __restrict__ Tf2, int ntiles16) {
  __shared__ unsigned lmx[2][128];
  const int t = threadIdx.x;
  if (t < 256) ((unsigned*)lmx)[t] = 0u;
  __syncthreads();
  const int w = t >> 6, l = t & 63;
  const int lm = l & 15, lg = l >> 4;
  const int tile = blockIdx.x * 4 + w;
  if (tile < ntiles16) {
    const int mbase = tile * 16;
    Frag A0, A1;                        // z[node][0:32], z[node][32:64] as f16
    {
      const float* zr = z + (size_t)(mbase + lm) * 64 + lg * 8;
      f32x4 v0 = *(const f32x4*)zr;
      f32x4 v1 = *(const f32x4*)(zr + 4);
      f32x4 v2 = *(const f32x4*)(zr + 32);
      f32x4 v3 = *(const f32x4*)(zr + 36);
      A0.u[0] = packhf(v0[0], v0[1]); A0.u[1] = packhf(v0[2], v0[3]);
      A0.u[2] = packhf(v1[0], v1[1]); A0.u[3] = packhf(v1[2], v1[3]);
      A1.u[0] = packhf(v2[0], v2[1]); A1.u[1] = packhf(v2[2], v2[3]);
      A1.u[2] = packhf(v3[0], v3[1]); A1.u[3] = packhf(v3[2], v3[3]);
    }
    #pragma unroll
    for (int h = 0; h < 2; ++h) {
      Frag Bf[2][8];
      #pragma unroll
      for (int ks = 0; ks < 2; ++ks)
        #pragma unroll
        for (int nt = 0; nt < 8; ++nt)
          Bf[ks][nt].q = *(const u32x4*)(W1h +
              ((size_t)(h*16 + ks*8 + nt) * 64 + l) * 8);
      f32x4 acc[8];
      #pragma unroll
      for (int nt = 0; nt < 8; ++nt) {
        float iv = h ? 0.f : kvbuf[nt * 16 + lm];
        f32x4 z4 = {iv, iv, iv, iv};
        acc[nt] = z4;
      }
      #pragma unroll
      for (int nt = 0; nt < 8; ++nt) {
        acc[nt] = __builtin_amdgcn_mfma_f32_16x16x32_f16(A0.h, Bf[0][nt].h, acc[nt], 0, 0, 0);
        acc[nt] = __builtin_amdgcn_mfma_f32_16x16x32_f16(A1.h, Bf[1][nt].h, acc[nt], 0, 0, 0);
      }
      float* Tf = h ? Tf2 : Tf1;
      #pragma unroll
      for (int nt = 0; nt < 8; ++nt) {
        float m = fmaxf(fmaxf(fabsf(acc[nt][0]), fabsf(acc[nt][1])),
                        fmaxf(fabsf(acc[nt][2]), fabsf(acc[nt][3])));
        atomicMax(&lmx[h][nt*16 + lm], __float_as_uint(m));
        #pragma unroll
        for (int r = 0; r < 4; ++r)
          __builtin_nontemporal_store(acc[nt][r],
              Tf + (size_t)(mbase + lg*4 + r) * 128 + nt*16 + lm);
      }
    }
  }
  __syncthreads();
  if (t < 128) atomicMax(&gmax1[t], lmx[0][t]);
  else         atomicMax(&gmax2[t - 128], lmx[1][t - 128]);
}

// ---------------- kernel 1b: streaming quantize Tf -> permuted u8 -----
__global__ __launch_bounds__(256) void k_quant(
    const float* __restrict__ Tf1, const float* __restrict__ Tf2,
    const unsigned* __restrict__ g1, const unsigned* __restrict__ g2,
    unsigned char* __restrict__ U1, unsigned char* __restrict__ U2,
    int n_nodes) {
  const int tid = blockIdx.x * 256 + threadIdx.x;
  const int tot = n_nodes * 8;
  if (tid >= 2 * tot) return;
  const int table = tid >= tot;
  const int r = tid - table * tot;
  const int node = r >> 3, g = r & 7;
  const float* src = (table ? Tf2 : Tf1) + (size_t)node * 128 + g * 16;
  unsigned char* dst = (table ? U2 : U1) + (size_t)node * 128;
  f32x4 v[4];
  #pragma unroll
  for (int q = 0; q < 4; ++q)
    v[q] = __builtin_nontemporal_load((const f32x4*)(src + q * 4));
  #pragma unroll
  for (int b = 0; b < 2; ++b) {
    unsigned w0 = 0, w1 = 0;
    #pragma unroll
    for (int k = 0; k < 8; ++k) {
      const int f = g * 16 + b * 8 + k;
      float m = fmaxf(fmaxf(__uint_as_float(g1[f]), __uint_as_float(g2[f])),
                      1e-20f);
      float dij = 127.0f / m;
      float acc = v[b * 2 + (k >> 2)][k & 3];
      int q8 = (int)rintf(acc * dij);
      q8 = q8 > 127 ? 127 : (q8 < -127 ? -127 : q8);
      unsigned by = (unsigned)(q8 + 128);
      if (k < 4) w0 |= by << (8 * k); else w1 |= by << (8 * (k - 4));
    }
    const int off = (((2 * g + b) & 3) * 32) + ((g >> 1) * 8);
    *(unsigned*)(dst + off)     = w0;
    *(unsigned*)(dst + off + 4) = w1;
  }
}

// ---------------- kernel 2: BN stats, 2-deep gather pipeline ----------
template<int WH8>
__global__ __launch_bounds__(512) void k_stats(
    const int* __restrict__ ei, const unsigned char* __restrict__ U1,
    const unsigned char* __restrict__ U2,
    unsigned long long* __restrict__ gstat,
    unsigned char* __restrict__ H8, int E, int niter16) {
  __shared__ int red[8][256];
  const int t = threadIdx.x;
  const int w = t >> 6, l = t & 63;
  const int es = l >> 3, ch = l & 7;
  int sm[16], sq[16];
  #pragma unroll
  for (int k = 0; k < 16; ++k) { sm[k] = 0; sq[k] = 0; }
  const int nw = gridDim.x * 8;
  int itc = blockIdx.x * 8 + w;
  int itn = itc + nw;
  u32x4 a0c, b0c, a1c, b1c, a0n, b0n, a1n, b1n;
  int ns0 = 0, nd0 = 0, ns1 = 0, nd1 = 0;
  if (itc < niter16) {
    const int e = itc * 16;
    int s0 = ei[e + es],     d0 = ei[E + e + es];
    int s1 = ei[e + 8 + es], d1 = ei[E + e + 8 + es];
    a0c = *(const u32x4*)(U1 + (size_t)s0 * 128 + ch * 16);
    b0c = *(const u32x4*)(U2 + (size_t)d0 * 128 + ch * 16);
    a1c = *(const u32x4*)(U1 + (size_t)s1 * 128 + ch * 16);
    b1c = *(const u32x4*)(U2 + (size_t)d1 * 128 + ch * 16);
  }
  if (itn < niter16) {
    const int e = itn * 16;
    ns0 = ei[e + es];     nd0 = ei[E + e + es];
    ns1 = ei[e + 8 + es]; nd1 = ei[E + e + 8 + es];
  }
  while (itc < niter16) {
    const bool vn = itn < niter16;
    if (vn) {
      a0n = *(const u32x4*)(U1 + (size_t)ns0 * 128 + ch * 16);
      b0n = *(const u32x4*)(U2 + (size_t)nd0 * 128 + ch * 16);
      a1n = *(const u32x4*)(U1 + (size_t)ns1 * 128 + ch * 16);
      b1n = *(const u32x4*)(U2 + (size_t)nd1 * 128 + ch * 16);
      const int it2 = itn + nw;
      if (it2 < niter16) {
        const int e = it2 * 16;
        ns0 = ei[e + es];     nd0 = ei[E + e + es];
        ns1 = ei[e + 8 + es]; nd1 = ei[E + e + 8 + es];
      }
    }
    const int e16 = itc * 16;
    u32x4 o0, o1;
    #pragma unroll
    for (int qq = 0; qq < 4; ++qq) {
      int h[4];
      dec4i(a0c[qq], b0c[qq], h);
      #pragma unroll
      for (int r = 0; r < 4; ++r) { sm[qq*4+r] += h[r]; sq[qq*4+r] += h[r]*h[r]; }
      if (WH8) o0[qq] = (unsigned)h[0] | ((unsigned)h[2] << 8)
                      | ((unsigned)h[1] << 16) | ((unsigned)h[3] << 24);
      dec4i(a1c[qq], b1c[qq], h);
      #pragma unroll
      for (int r = 0; r < 4; ++r) { sm[qq*4+r] += h[r]; sq[qq*4+r] += h[r]*h[r]; }
      if (WH8) o1[qq] = (unsigned)h[0] | ((unsigned)h[2] << 8)
                      | ((unsigned)h[1] << 16) | ((unsigned)h[3] << 24);
    }
    if (WH8) {
      *(u32x4*)(H8 + (size_t)(e16 + es) * 128 + ch * 16)     = o0;
      *(u32x4*)(H8 + (size_t)(e16 + 8 + es) * 128 + ch * 16) = o1;
    }
    if (!vn) break;
    a0c = a0n; b0c = b0n; a1c = a1n; b1c = b1n;
    itc = itn; itn += nw;
  }
  #pragma unroll
  for (int k = 0; k < 16; ++k) {
    sm[k] += __shfl_xor(sm[k], 8, 64);
    sm[k] += __shfl_xor(sm[k], 16, 64);
    sm[k] += __shfl_xor(sm[k], 32, 64);
    sq[k] += __shfl_xor(sq[k], 8, 64);
    sq[k] += __shfl_xor(sq[k], 16, 64);
    sq[k] += __shfl_xor(sq[k], 32, 64);
  }
  if (es == 0) {
    #pragma unroll
    for (int k = 0; k < 16; ++k) {
      int f = ((ch & 1) * 2 + (k >> 3)) * 32 + (ch >> 1) * 8 + (k & 7);
      red[w][f]       = sm[k];
      red[w][128 + f] = sq[k];
    }
  }
  __syncthreads();
  if (t < 256) {
    long long s = 0;
    #pragma unroll
    for (int ww = 0; ww < 8; ++ww) s += red[ww][t];
    atomicAdd(&gstat[t], (unsigned long long)s);
  }
}

// ---------------- kernel 3: finalize BN + fold scale into W2 ----------
__global__ __launch_bounds__(1024) void k_finalize(
    const unsigned long long* __restrict__ gstat,
    const float* __restrict__ gamma, const float* __restrict__ beta,
    const float* __restrict__ W2, const float* __restrict__ b2,
    const unsigned* __restrict__ gmax1, const unsigned* __restrict__ gmax2,
    unsigned short* __restrict__ W2t, float* __restrict__ b2p,
    float* __restrict__ b2ps, double Einv) {
  __shared__ float ajd[128], bbj[128];
  __shared__ float bacc[8][128];
  const int t = threadIdx.x;
  if (t < 128) {
    float m = fmaxf(fmaxf(__uint_as_float(gmax1[t]), __uint_as_float(gmax2[t])),
                    1e-20f);
    double d8 = (double)(m * (1.0f / 127.0f));
    double mean = d8 * (double)gstat[t] * Einv;
    double ex2  = d8 * d8 * (double)gstat[128 + t] * Einv;
    double var  = ex2 - mean * mean;
    float a = (float)((double)gamma[t] / sqrt(var + 1e-5));
    ajd[t] = a * (float)d8;
    bbj[t] = beta[t] - (float)mean * a;
  }
  __syncthreads();
  for (int cidx = t; cidx < 16384; cidx += 1024) {
    int i = cidx >> 7;
    int j = cidx & 127;
    W2t[j * 128 + i] = f2h(ajd[i] * W2[cidx]);
  }
  {
    const int col = t & 127, g2 = t >> 7;
    float acc = 0.f;
    #pragma unroll
    for (int q = 0; q < 16; ++q) {
      int i = g2 * 16 + q;
      acc += bbj[i] * W2[i * 128 + col];
    }
    bacc[g2][col] = acc;
  }
  __syncthreads();
  if (t < 128) {
    float a = b2[t];
    #pragma unroll
    for (int g3 = 0; g3 < 8; ++g3) a += bacc[g3][t];
    b2p[t] = a;
    float c = 0.f;
    for (int i = 0; i < 128; ++i)
      c += (float)((_Float16)(ajd[i] * W2[i * 128 + t]));
    b2ps[t] = a - 1024.0f * c;
  }
}

// ---------------- kernel 4: streaming MFMA over H8, B in registers ----
__global__ __launch_bounds__(256) void k_edge_h8(
    const unsigned char* __restrict__ H8, const unsigned short* __restrict__ W2t,
    const float* __restrict__ b2ps, const float* __restrict__ W3,
    const float* __restrict__ b3, float* __restrict__ out, int ntiles) {
  const int t = threadIdx.x;
  const int w = t >> 6, l = t & 63;
  const int lm = l & 15, lg = l >> 4;
  const int lo32 = lg * 32;
  Frag Bf[8][4];
  #pragma unroll
  for (int nt = 0; nt < 8; ++nt)
    #pragma unroll
    for (int s = 0; s < 4; ++s)
      Bf[nt][s].q = *(const u32x4*)((const char*)W2t +
                      (size_t)(nt*16 + lm) * 256 + s*64 + lg*16);
  float b2r[8], w3r[8];
  #pragma unroll
  for (int nt = 0; nt < 8; ++nt) {
    b2r[nt] = b2ps[nt*16 + lm];
    w3r[nt] = W3[nt*16 + lm];
  }
  const float b3v = *b3;
  const int stride = gridDim.x;
  int tile = blockIdx.x;
  if (tile >= ntiles) return;
  int ebase = tile*64 + w*16;
  u32x4 Y0, Y1, N0, N1;
  {
    const unsigned char* r0 = H8 + (size_t)(ebase + lm) * 128 + lo32;
    Y0 = *(const u32x4*)r0;  Y1 = *(const u32x4*)(r0 + 16);
  }
  while (true) {
    const int next = tile + stride;
    const bool has_next = next < ntiles;
    const int pref = has_next ? next : tile;
    const int neb = pref*64 + w*16;
    {
      const unsigned char* n0 = H8 + (size_t)(neb + lm) * 128 + lo32;
      N0 = *(const u32x4*)n0;  N1 = *(const u32x4*)(n0 + 16);
    }
    f32x4 acc[8];
    #pragma unroll
    for (int nt = 0; nt < 8; ++nt) {
      f32x4 zed = {0.f, 0.f, 0.f, 0.f};
      acc[nt] = zed;
    }
    Frag fa;
    #define MFMAS(S)                                                        \
      _Pragma("unroll")                                                     \
      for (int nt = 0; nt < 8; ++nt)                                        \
        acc[nt] = __builtin_amdgcn_mfma_f32_16x16x32_f16(fa.h, Bf[nt][S].h, \
                                                         acc[nt], 0, 0, 0);
    mg2(Y0[0], fa.u[0], fa.u[1]); mg2(Y0[1], fa.u[2], fa.u[3]);
    MFMAS(0)
    mg2(Y0[2], fa.u[0], fa.u[1]); mg2(Y0[3], fa.u[2], fa.u[3]);
    MFMAS(1)
    mg2(Y1[0], fa.u[0], fa.u[1]); mg2(Y1[1], fa.u[2], fa.u[3]);
    MFMAS(2)
    mg2(Y1[2], fa.u[0], fa.u[1]); mg2(Y1[3], fa.u[2], fa.u[3]);
    MFMAS(3)
    #undef MFMAS
    #pragma unroll
    for (int r = 0; r < 4; ++r) {
      float sum = 0.f;
      #pragma unroll
      for (int nt = 0; nt < 8; ++nt) {
        float h2 = fmaxf(acc[nt][r] + b2r[nt], 0.f);
        sum += h2 * w3r[nt];
      }
      sum = dppadd<0xB1>(sum);
      sum = dppadd<0x4E>(sum);
      sum += __shfl_xor(sum, 4, 64);
      sum += __shfl_xor(sum, 8, 64);
      if (lm == 0) out[ebase + lg*4 + r] = sum + b3v;
    }
    if (!has_next) break;
    tile = next;
    ebase = neb;
    Y0 = N0;  Y1 = N1;
  }
}

extern "C" void kernel_launch(void* const* d_in, const int* in_sizes, int n_in,
                              void* d_out, int out_size, void* d_ws, size_t ws_size,
                              hipStream_t stream) {
  const float* z     = (const float*)d_in[0];
  const int*   ei    = (const int*)d_in[1];
  const float* c     = (const float*)d_in[2];
  const float* W1    = (const float*)d_in[3];
  const float* b1    = (const float*)d_in[4];
  const float* gamma = (const float*)d_in[5];
  const float* beta  = (const float*)d_in[6];
  const float* W2    = (const float*)d_in[7];
  const float* b2    = (const float*)d_in[8];
  const float* W3    = (const float*)d_in[9];
  const float* b3    = (const float*)d_in[10];
  float* out = (float*)d_out;

  const int n_nodes = in_sizes[0] / 64;   // 50000
  const int E       = in_sizes[1] / 2;    // 1600000
  const int NB2 = 1024;

  char* ws = (char*)d_ws;
  const size_t nb128 = (size_t)n_nodes * 128;   // 6.4 MB per table
  unsigned char* U1 = (unsigned char*)ws;
  unsigned char* U2 = U1 + nb128;
  char* p = (char*)(U2 + nb128);
  unsigned short* W2t = (unsigned short*)p;      p += 32768;
  unsigned short* W1h = (unsigned short*)p;      p += 32768;
  float* kvbuf        = (float*)p;               p += 512;
  float* b2p          = (float*)p;               p += 512;
  float* b2ps         = (float*)p;               p += 512;
  unsigned* gmax1     = (unsigned*)p;            p += 512;
  unsigned* gmax2     = (unsigned*)p;            p += 512;
  unsigned long long* gstat = (unsigned long long*)p;  p += 2048;
  unsigned char* H8   = (unsigned char*)p;
  // Tf (f32 projections, 51.2 MB) lives in the H8 region: consumed by
  // k_quant BEFORE k_stats overwrites H8. Union is safe (stream-ordered).
  float* Tf1 = (float*)H8;
  float* Tf2 = Tf1 + (size_t)n_nodes * 128;
  const size_t need = (size_t)((char*)H8 - ws) + (size_t)E * 128;  // ~218 MB
  const bool use_h8 = (ws_size >= need);

  // zero gmax1(512) + gmax2(512) + gstat(2048) in one contiguous memset
  (void)hipMemsetAsync(gmax1, 0, 3072, stream);
  k_wprep<<<8, 256, 0, stream>>>(W1, b1, c, W1h, kvbuf);
  const int ntiles16 = n_nodes / 16;             // 3125 (exact)
  k_npmfma<<<(ntiles16 + 3) / 4, 256, 0, stream>>>(z, W1h, kvbuf, gmax1, gmax2,
                                                   Tf1, Tf2, ntiles16);
  const int nqb = (n_nodes * 16 + 255) / 256;
  k_quant<<<nqb, 256, 0, stream>>>(Tf1, Tf2, gmax1, gmax2, U1, U2, n_nodes);
  if (use_h8)
    k_stats<1><<<NB2, 512, 0, stream>>>(ei, U1, U2, gstat, H8, E, E/16);
  else
    k_stats<0><<<NB2, 512, 0, stream>>>(ei, U1, U2, gstat, H8, E, E/16);
  k_finalize<<<1, 1024, 0, stream>>>(gstat, gamma, beta, W2, b2,
                                     gmax1, gmax2, W2t, b2p, b2ps,
                                     1.0 / (double)E);
  k_edge_h8<<<512, 256, 0, stream>>>(H8, W2t, b2ps, W3, b3, out, E/64);
}